// Round 6
// baseline (112.362 us; speedup 1.0000x reference)
//
#include <hip/hip_runtime.h>

// PCEN [B=64,C=128,T=4000] f32: M_t = 0.975 M_{t-1} + 0.025 x_t (M_{-1}=0);
//   y = sqrt(x * (M+1e-6)^-0.98 + 2) - sqrt(2)
// R6: R4 structure (EPL=4, tile=256, wave-parallel affine scan) with:
//  (a) 2 waves per row -- wave A: t in [0,2048) exact; wave B: one warmup scan-tile
//      [1792,2048) from M=0 (err ~0.975^256 = 1.5e-3 << 9.7e-2 threshold), then
//      t in [2048,4000). Halves per-wave serial tile chain: 16 -> ~8.7.
//  (b) non-temporal y stores: y (128MB) never re-read; nt keeps it from thrashing
//      the 256MB L3 so x (131MB) stays L3-resident -> FETCH drops.

#define T_LEN 4000
#define TILE  256
#define HALF  2048              // wave A covers 8 tiles
#define NT2   7                 // full tiles in wave B ([2048,3840))
#define TAILL 40                // active lanes in 160-elem tail [3840,4000)

typedef float f32x4 __attribute__((ext_vector_type(4)));

constexpr double dpow(double b, int e) { double r = 1.0; for (int i = 0; i < e; ++i) r *= b; return r; }

__device__ const float S    = 0.025f;
__device__ const float OMS  = 0.975f;
#define K1   ((float)dpow(0.975, 4))
#define K2   ((float)dpow(0.975, 8))
#define K4   ((float)dpow(0.975, 16))
#define K8   ((float)dpow(0.975, 32))
#define K16  ((float)dpow(0.975, 64))
#define K32  ((float)dpow(0.975, 128))
#define KT   ((float)dpow(0.975, 256))
#define INVK ((float)(1.0 / dpow(0.975, 4)))

__device__ __forceinline__ float pcen_y(float x, float M) {
    float p = __builtin_amdgcn_exp2f(-0.98f * __builtin_amdgcn_logf(M + 1e-6f));
    return sqrtf(fmaf(x, p, 2.0f)) - 1.41421356237309515f;
}

// One 256-t tile: scan + (optionally) emit y. Returns updated cross-tile carry M0.
template<bool WR, bool MASKED>
__device__ __forceinline__ float do_tile(f32x4 v, float* __restrict__ dst,
                                         float M0, int lane, float c, bool act) {
    // lane-local affine offset from M=0
    float b = S * v.x;
    b = fmaf(S, v.y, OMS * b);
    b = fmaf(S, v.z, OMS * b);
    b = fmaf(S, v.w, OMS * b);

    // inclusive geometric scan across lanes, K = 0.975^4
    float I = b, tv;
    tv = __shfl_up(I, 1);  I = fmaf(K1,  (lane >= 1  ? tv : 0.0f), I);
    tv = __shfl_up(I, 2);  I = fmaf(K2,  (lane >= 2  ? tv : 0.0f), I);
    tv = __shfl_up(I, 4);  I = fmaf(K4,  (lane >= 4  ? tv : 0.0f), I);
    tv = __shfl_up(I, 8);  I = fmaf(K8,  (lane >= 8  ? tv : 0.0f), I);
    tv = __shfl_up(I, 16); I = fmaf(K16, (lane >= 16 ? tv : 0.0f), I);
    tv = __shfl_up(I, 32); I = fmaf(K32, (lane >= 32 ? tv : 0.0f), I);

    if (WR) {
        // exclusive carry-in: E = (I-b)/K ; then replay 4 elements
        float M = fmaf(c, M0, (I - b) * INVK);
        f32x4 o;
        M = fmaf(S, v.x, OMS * M);  o.x = pcen_y(v.x, M);
        M = fmaf(S, v.y, OMS * M);  o.y = pcen_y(v.y, M);
        M = fmaf(S, v.z, OMS * M);  o.z = pcen_y(v.z, M);
        M = fmaf(S, v.w, OMS * M);  o.w = pcen_y(v.w, M);
        if (!MASKED || act)
            __builtin_nontemporal_store(o, reinterpret_cast<f32x4*>(dst));
    }

    const float Ilast = __shfl(I, 63);
    return fmaf(KT, M0, Ilast);
}

__global__ __launch_bounds__(256) void pcen_kernel(const float* __restrict__ x,
                                                   float* __restrict__ y) {
    const int wid  = threadIdx.x >> 6;
    const int lane = threadIdx.x & 63;
    const int row  = blockIdx.x * 2 + (wid >> 1);
    const int half = wid & 1;

    // c = 0.975^(4*lane)
    const float c = __builtin_amdgcn_exp2f((float)lane * (4.0f * -0.036525699374527566f));

    const float* __restrict__ xr = x + (size_t)row * T_LEN;
    float*       __restrict__ yr = y + (size_t)row * T_LEN;
    const int l4 = lane * 4;

    float M0 = 0.0f;

    if (half == 0) {
        // tiles 0..7, exact from M=0
        f32x4 vn = *reinterpret_cast<const f32x4*>(xr + l4);
        #pragma unroll
        for (int t = 0; t < 8; ++t) {
            const f32x4 v = vn;
            if (t + 1 < 8)
                vn = *reinterpret_cast<const f32x4*>(xr + (t + 1) * TILE + l4);
            M0 = do_tile<true, false>(v, yr + t * TILE + l4, M0, lane, c, true);
        }
    } else {
        // warmup tile [1792,2048) (no write), then tiles [2048,3840), then tail
        f32x4 vn = *reinterpret_cast<const f32x4*>(xr + (HALF - TILE) + l4);
        {
            const f32x4 v = vn;
            vn = *reinterpret_cast<const f32x4*>(xr + HALF + l4);
            M0 = do_tile<false, false>(v, nullptr, M0, lane, c, true);
        }
        const bool act = lane < TAILL;
        #pragma unroll
        for (int t = 0; t < NT2; ++t) {
            const f32x4 v = vn;
            if (t + 1 < NT2) {
                vn = *reinterpret_cast<const f32x4*>(xr + HALF + (t + 1) * TILE + l4);
            } else {
                vn = act ? *reinterpret_cast<const f32x4*>(xr + HALF + NT2 * TILE + l4)
                         : (f32x4){0.f, 0.f, 0.f, 0.f};
            }
            M0 = do_tile<true, false>(v, yr + HALF + t * TILE + l4, M0, lane, c, true);
        }
        // tail: 160 elements, lanes 0..39
        do_tile<true, true>(vn, yr + HALF + NT2 * TILE + l4, M0, lane, c, act);
    }
}

extern "C" void kernel_launch(void* const* d_in, const int* in_sizes, int n_in,
                              void* d_out, int out_size, void* d_ws, size_t ws_size,
                              hipStream_t stream) {
    const float* x = (const float*)d_in[0];
    float* y       = (float*)d_out;
    // 8192 rows x 2 half-waves = 16384 waves; 4 waves/block -> 4096 blocks
    pcen_kernel<<<4096, 256, 0, stream>>>(x, y);
}

// Round 7
// 52.488 us; speedup vs baseline: 2.1407x; 2.1407x over previous
//
#include <hip/hip_runtime.h>

// PCEN [B=64,C=128,T=4000] f32: M_t = 0.975 M_{t-1} + 0.025 x_t (M_{-1}=0);
//   y = sqrt(x * (M+1e-6)^-0.98 + 2) - sqrt(2)
// R7 = R4 (52.7us) with ONE change: the 6-step shfl_up scan (6 x ~50cy serial
// ds_bpermute) is replaced by a 6-step DPP weighted scan (in-pipe VALU, ~4-8cy):
//   row_shr:1/2/4/8 (bound_ctrl:0 zero-fills row-local OOB -> exactly our mask),
//   row_bcast15 -> rows 1,3 (per-lane mult K^((lane&15)+1)),
//   row_bcast31 -> rows 2,3 (per-lane mult K^((lane&31)+1)).
// Cross-tile carry via v_readlane(I,63). E=(I-b)/K carry trick (validated R6).
// Everything else identical to R4: EPL=4, tile=256, 1 wave/row, plain float4
// stores, prefetch 1 tile ahead, 2048 blocks x 256.

#define T_LEN 4000
#define TILE  256
#define NFULL (T_LEN / TILE)            // 15 full tiles
#define TAILL ((T_LEN - NFULL*TILE)/4)  // 40 active lanes in 160-elem tail

typedef float f32x4 __attribute__((ext_vector_type(4)));

constexpr double dpow(double b, int e) { double r = 1.0; for (int i = 0; i < e; ++i) r *= b; return r; }

// mov_dpp with old=0: masked-out / OOB lanes read 0.0f
template<int CTRL, int RMASK, bool BC>
__device__ __forceinline__ float dpp0(float x) {
    return __int_as_float(__builtin_amdgcn_update_dpp(
        0, __float_as_int(x), CTRL, RMASK, 0xf, BC));
}

__device__ __forceinline__ float pcen_y(float x, float M) {
    float p = __builtin_amdgcn_exp2f(-0.98f * __builtin_amdgcn_logf(M + 1e-6f));
    return sqrtf(fmaf(x, p, 2.0f)) - 1.41421356237309515f;
}

__global__ __launch_bounds__(256) void pcen_kernel(const float* __restrict__ x,
                                                   float* __restrict__ y) {
    const int wid  = threadIdx.x >> 6;
    const int lane = threadIdx.x & 63;
    const int row  = blockIdx.x * 4 + wid;

    const float S   = 0.025f, OMS = 0.975f;
    const float K1   = (float)dpow(0.975, 4);        // K = 0.975^4 (per-lane decay)
    const float K2   = (float)dpow(0.975, 8);
    const float K4   = (float)dpow(0.975, 16);
    const float K8   = (float)dpow(0.975, 32);
    const float KT   = (float)dpow(0.975, 256);      // whole-tile decay
    const float invK = (float)(1.0 / dpow(0.975, 4));

    const float L2K = -0.14610279749811041f;         // log2(0.975^4)
    // c  = K^lane          (carry decay to this lane)
    // m1 = K^((lane&15)+1) (row_bcast15 weight: distance from lane 15/47)
    // m2 = K^((lane&31)+1) (row_bcast31 weight: distance from lane 31)
    const float c  = __builtin_amdgcn_exp2f((float)lane * L2K);
    const float m1 = __builtin_amdgcn_exp2f((float)((lane & 15) + 1) * L2K);
    const float m2 = __builtin_amdgcn_exp2f((float)((lane & 31) + 1) * L2K);

    const float* __restrict__ xr = x + (size_t)row * T_LEN;
    float*       __restrict__ yr = y + (size_t)row * T_LEN;
    const int l4 = lane * 4;

    float M0 = 0.0f;
    f32x4 vn = *reinterpret_cast<const f32x4*>(xr + l4);   // prefetch tile 0

    for (int t = 0; t < NFULL; ++t) {
        const f32x4 v = vn;
        if (t + 1 < NFULL)
            vn = *reinterpret_cast<const f32x4*>(xr + (t + 1) * TILE + l4);

        // lane-local affine offset from M=0
        float b = S * v.x;
        b = fmaf(S, v.y, OMS * b);
        b = fmaf(S, v.z, OMS * b);
        b = fmaf(S, v.w, OMS * b);

        // 64-lane weighted inclusive scan, all in the VALU pipe (DPP)
        float I = b, tv;
        tv = dpp0<0x111, 0xf, true >(I);  I = fmaf(K1, tv, I);   // row_shr:1
        tv = dpp0<0x112, 0xf, true >(I);  I = fmaf(K2, tv, I);   // row_shr:2
        tv = dpp0<0x114, 0xf, true >(I);  I = fmaf(K4, tv, I);   // row_shr:4
        tv = dpp0<0x118, 0xf, true >(I);  I = fmaf(K8, tv, I);   // row_shr:8
        tv = dpp0<0x142, 0xa, false>(I);  I = fmaf(m1, tv, I);   // bcast15 -> rows 1,3
        tv = dpp0<0x143, 0xc, false>(I);  I = fmaf(m2, tv, I);   // bcast31 -> rows 2,3

        // exclusive carry-in E = (I-b)/K, then replay 4 elements
        float M = fmaf(c, M0, (I - b) * invK);
        f32x4 o;
        M = fmaf(S, v.x, OMS * M);  o.x = pcen_y(v.x, M);
        M = fmaf(S, v.y, OMS * M);  o.y = pcen_y(v.y, M);
        M = fmaf(S, v.z, OMS * M);  o.z = pcen_y(v.z, M);
        M = fmaf(S, v.w, OMS * M);  o.w = pcen_y(v.w, M);
        *reinterpret_cast<f32x4*>(yr + t * TILE + l4) = o;

        // cross-tile carry: inclusive total of lane 63
        const float Ilast = __int_as_float(
            __builtin_amdgcn_readlane(__float_as_int(I), 63));
        M0 = fmaf(KT, M0, Ilast);
    }

    // tail: 160 elements, lanes 0..39 active
    {
        const bool act = lane < TAILL;
        f32x4 v = {0.f, 0.f, 0.f, 0.f};
        if (act) v = *reinterpret_cast<const f32x4*>(xr + NFULL * TILE + l4);

        float b = S * v.x;
        b = fmaf(S, v.y, OMS * b);
        b = fmaf(S, v.z, OMS * b);
        b = fmaf(S, v.w, OMS * b);

        float I = b, tv;
        tv = dpp0<0x111, 0xf, true >(I);  I = fmaf(K1, tv, I);
        tv = dpp0<0x112, 0xf, true >(I);  I = fmaf(K2, tv, I);
        tv = dpp0<0x114, 0xf, true >(I);  I = fmaf(K4, tv, I);
        tv = dpp0<0x118, 0xf, true >(I);  I = fmaf(K8, tv, I);
        tv = dpp0<0x142, 0xa, false>(I);  I = fmaf(m1, tv, I);
        tv = dpp0<0x143, 0xc, false>(I);  I = fmaf(m2, tv, I);

        float M = fmaf(c, M0, (I - b) * invK);
        f32x4 o;
        M = fmaf(S, v.x, OMS * M);  o.x = pcen_y(v.x, M);
        M = fmaf(S, v.y, OMS * M);  o.y = pcen_y(v.y, M);
        M = fmaf(S, v.z, OMS * M);  o.z = pcen_y(v.z, M);
        M = fmaf(S, v.w, OMS * M);  o.w = pcen_y(v.w, M);
        if (act)
            *reinterpret_cast<f32x4*>(yr + NFULL * TILE + l4) = o;
    }
}

extern "C" void kernel_launch(void* const* d_in, const int* in_sizes, int n_in,
                              void* d_out, int out_size, void* d_ws, size_t ws_size,
                              hipStream_t stream) {
    const float* x = (const float*)d_in[0];
    float* y       = (float*)d_out;
    pcen_kernel<<<8192 / 4, 256, 0, stream>>>(x, y);  // 2048 blocks, 4 rows/block
}